// Round 3
// baseline (488.967 us; speedup 1.0000x reference)
//
#include <hip/hip_runtime.h>
#include <math.h>

// ---------------------------------------------------------------------------
// Sparse_Attn_Logic — round 3.
// R2 evidence: branches_kernel 218us, VALUBusy 15%, 1.57M LDS bank conflicts,
// FETCH fixed at 2.1MB -> LDS-issue + barrier-coupling bound (~1150 scalar
// ds_read_b32 per wave, 16 block-wide barriers). This round: all LDS access
// vectorized to b128/b64 at conflict-free strides (~110 LDS instrs/wave),
// inter-stage __syncthreads removed (wave-private scratch, program-order +
// lgkmcnt suffices; wave_barrier as scheduling fence).
// ---------------------------------------------------------------------------

#define B_SZ 1024
#define C_CH 32
#define L_POOL 520
#define L_S1 257
#define L_S2 125
#define L_MP 31

// ---------------- K0: zero the fp64 accumulators --------------------------
__global__ void zero_stats_kernel(double* d) {
    int i = threadIdx.x;
    if (i < 160) d[i] = 0.0;
}

// ---------------- K1: x statistics (Sx, C[0..15]) -------------------------
__global__ __launch_bounds__(256) void xstats_kernel(
    const float* __restrict__ x, double* __restrict__ stats)
{
    __shared__ __align__(16) float xr[1040];   // 16-float zero tail: no bounds check
    __shared__ float wred[4][17];
    int b = blockIdx.x, tid = threadIdx.x;
    for (int i = tid; i < 1024; i += 256) xr[i] = x[b * 1024 + i];
    if (tid < 16) xr[1024 + tid] = 0.f;
    __syncthreads();
    float acc[17];
#pragma unroll
    for (int d = 0; d < 17; ++d) acc[d] = 0.f;
    for (int p = tid; p < 1024; p += 256) {
        float v = xr[p];
        acc[16] += v;
#pragma unroll
        for (int d = 0; d < 16; ++d)
            acc[d] += v * xr[p + d];
    }
#pragma unroll
    for (int off = 32; off >= 1; off >>= 1)
#pragma unroll
        for (int d = 0; d < 17; ++d)
            acc[d] += __shfl_down(acc[d], off);
    int wave = tid >> 6, lane = tid & 63;
    if (lane == 0)
        for (int d = 0; d < 17; ++d) wred[wave][d] = acc[d];
    __syncthreads();
    if (tid < 17) {
        double tot = (double)wred[0][tid] + (double)wred[1][tid]
                   + (double)wred[2][tid] + (double)wred[3][tid];
        atomicAdd(&stats[tid], tot);
    }
}

// ---------------- K2: filters + analytic BN1 ------------------------------
__global__ __launch_bounds__(512) void prep_kernel(
    const double* __restrict__ stats,
    const float* __restrict__ la_a, const float* __restrict__ la_b,
    const float* __restrict__ bn1_g, const float* __restrict__ bn1_b,
    float* __restrict__ g18_out, float* __restrict__ a1d1_out)
{
    __shared__ float fs[32][16];
    int tid = threadIdx.x;
    if (tid < 512) {
        int c = tid >> 4, k = tid & 15;
        const double A = 0.08, ep = 0.03, tal = 0.1;
        const double w = 2.0 * 3.14159265358979323846 * 50.0;
        const double q = 1.0 - ep * ep;
        double t = (double)k / 15.0;
        double p = t - (double)la_b[c] / (double)la_a[c];
        double arg = w * (p - tal);
        double y = A * exp(-ep / sqrt(q) * arg) * (-sin(arg));
        fs[c][k] = (float)y;
    }
    __syncthreads();
    if (tid < 32) {
        int c = tid;
        for (int i = 0; i < 18; ++i) {
            float g = 0.f;
            for (int k = i - 2; k <= i; ++k)
                if (k >= 0 && k < 16) g += fs[c][k];
            g18_out[c * 18 + i] = g;
        }
        double Sf = 0.0;
        for (int k = 0; k < 16; ++k) Sf += (double)fs[c][k];
        double E2 = 0.0;
        for (int k = 0; k < 16; ++k)
            for (int k2 = 0; k2 < 16; ++k2)
                E2 += (double)fs[c][k] * (double)fs[c][k2]
                    * stats[k > k2 ? k - k2 : k2 - k];
        const double N = 1024.0 * 1041.0;
        double Sx = stats[16];
        double mc  = Sx * Sf / N;
        double var = E2 / N - mc * mc;
        double invstd = 1.0 / sqrt(var + 1e-5);
        float alpha = bn1_g[c] * (float)invstd;
        a1d1_out[c]      = alpha / 3.0f;
        a1d1_out[32 + c] = bn1_b[c] - (float)mc * alpha;
    }
}

// ---------------- K3: fused conv+BN+pool + both branches ------------------
// One block per b; 8 waves; wave wv handles channels wv, wv+8, wv+16, wv+24.
// All LDS traffic is b128/b64 at conflict-free strides; no block barriers
// inside the channel loop (scratch is wave-private).
#define SCR_ROW 1296   // hr@0 (520) | x1@520 (260) | x2@780 (260) | y1@1040 (128) | y2@1168 (128)
__global__ __launch_bounds__(512) void branches_kernel(
    const float* __restrict__ x,
    const float* __restrict__ g18g, const float* __restrict__ a1d1,
    const float* __restrict__ a1w_g, const float* __restrict__ a1b_g,
    const float* __restrict__ e1w_g, const float* __restrict__ e1b_g,
    const float* __restrict__ f1w_g, const float* __restrict__ f1b_g,
    const float* __restrict__ faw_g, const float* __restrict__ fab_g,
    float* __restrict__ p1, float* __restrict__ p2,
    double* __restrict__ bn_d)
{
    __shared__ __align__(16) float xr[1072];      // [0..15]=0, x @16, zeros @1040+
    __shared__ __align__(16) float scr[8][SCR_ROW];
    __shared__ __align__(16) float g18s[32][18];
    __shared__ __align__(16) float wts[4][32][8]; // 0=a1w 1=e1w 2=f1w 3=faw

    int b = blockIdx.x, t = threadIdx.x;
    int wv = t >> 6, lane = t & 63;

    {
        float2 v = ((const float2*)(x + (size_t)b * 1024))[t];
        xr[16 + 2 * t] = v.x;
        xr[17 + 2 * t] = v.y;
        if (t < 16) xr[t] = 0.f;
        if (t < 32) xr[1040 + t] = 0.f;
    }
    if (t < 288) ((float2*)&g18s[0][0])[t] = ((const float2*)g18g)[t];
    if (t < 256) {
        wts[0][0][t] = a1w_g[t];
        wts[1][0][t] = e1w_g[t];
        wts[2][0][t] = f1w_g[t];
        wts[3][0][t] = faw_g[t];
    }
    __syncthreads();   // the only block-wide barrier

    float* hr  = scr[wv];
    float* x1s = scr[wv] + 520;
    float* x2s = scr[wv] + 780;
    float* y1s = scr[wv] + 1040;
    float* y2s = scr[wv] + 1168;

    for (int cc = 0; cc < 4; ++cc) {
        int c = (cc << 3) + wv;
        float alpha = a1d1[c], delta = a1d1[32 + c];

        float g[18];
#pragma unroll
        for (int i = 0; i < 18; ++i) g[i] = g18s[c][i];

        // ---- conv + BN1 + avgpool: 8 consecutive outputs per lane --------
        // window xr[16*lane .. 16*lane+31] via 8 ds_read_b128
        float xw[32];
        {
            const float4* xp = (const float4*)&xr[16 * lane];
#pragma unroll
            for (int q = 0; q < 8; ++q) {
                float4 v = xp[q];
                xw[4 * q] = v.x; xw[4 * q + 1] = v.y;
                xw[4 * q + 2] = v.z; xw[4 * q + 3] = v.w;
            }
        }
        float hv[8];
#pragma unroll
        for (int jj = 0; jj < 8; ++jj) {
            float s = 0.f;
#pragma unroll
            for (int i = 0; i < 18; ++i) s += g[i] * xw[2 * jj + i];
            hv[jj] = s * alpha + delta;
        }
        *(float4*)&hr[8 * lane]     = make_float4(hv[0], hv[1], hv[2], hv[3]);
        *(float4*)&hr[8 * lane + 4] = make_float4(hv[4], hv[5], hv[6], hv[7]);
        if (lane < 8) {                 // tail outputs j = 512..519
            int j = 512 + lane;
            float s = 0.f;
#pragma unroll
            for (int i = 0; i < 18; ++i) s += g[i] * xr[2 * j + i];
            hr[j] = s * alpha + delta;
        }
        __builtin_amdgcn_wave_barrier();

        float wa[8], we[8], wf[8], wfa[8];
        float A1 = a1b_g[c], E1 = 1.f - e1b_g[c];
        float F1 = 1.f - f1b_g[c], FA = fab_g[c];
#pragma unroll
        for (int k = 0; k < 8; ++k) {
            wa[k]  = wts[0][c][k]; we[k]  = wts[1][c][k];
            wf[k]  = wts[2][c][k]; wfa[k] = wts[3][c][k];
            A1 -= wa[k]; FA -= wfa[k];
        }

        // ---- stage 1: Always(a1) & Eventually(f1), 4 outputs/lane --------
        // window hr[8*lane .. 8*lane+15] via 4 b128 (stride 32B, conflict-free)
        float hw[16];
        {
            const float4* hp = (const float4*)&hr[8 * lane];
#pragma unroll
            for (int q = 0; q < 4; ++q) {
                float4 v = hp[q];
                hw[4 * q] = v.x; hw[4 * q + 1] = v.y;
                hw[4 * q + 2] = v.z; hw[4 * q + 3] = v.w;
            }
        }
        float x1v[4], x2v[4];
#pragma unroll
        for (int nn = 0; nn < 4; ++nn) {
            float s1 = A1, s2 = F1;
#pragma unroll
            for (int k = 0; k < 8; ++k) {
                float h = hw[2 * nn + k];
                s1 += h * wa[k];
                s2 += h * wf[k];
            }
            x1v[nn] = s1 > 0.f ? s1 : 0.f;
            x2v[nn] = s2 > 0.f ? s2 : 0.f;
        }
        *(float4*)&x1s[4 * lane] = make_float4(x1v[0], x1v[1], x1v[2], x1v[3]);
        *(float4*)&x2s[4 * lane] = make_float4(x2v[0], x2v[1], x2v[2], x2v[3]);
        if (lane == 0) {                // tail output n = 256
            float s1 = A1, s2 = F1;
#pragma unroll
            for (int k = 0; k < 8; ++k) {
                float h = hr[512 + k];
                s1 += h * wa[k];
                s2 += h * wf[k];
            }
            x1s[256] = s1 > 0.f ? s1 : 0.f;
            x2s[256] = s2 > 0.f ? s2 : 0.f;
        }
        __builtin_amdgcn_wave_barrier();

        // ---- stage 2: Eventually(e1) & Always(fa), 2 outputs/lane --------
        // window x?s[4*lane .. 4*lane+11] via 3 b128 (stride 16B, conflict-free)
        float u1[12], u2[12];
        {
            const float4* q1p = (const float4*)&x1s[4 * lane];
            const float4* q2p = (const float4*)&x2s[4 * lane];
#pragma unroll
            for (int q = 0; q < 3; ++q) {
                float4 v = q1p[q];
                u1[4 * q] = v.x; u1[4 * q + 1] = v.y;
                u1[4 * q + 2] = v.z; u1[4 * q + 3] = v.w;
                float4 u = q2p[q];
                u2[4 * q] = u.x; u2[4 * q + 1] = u.y;
                u2[4 * q + 2] = u.z; u2[4 * q + 3] = u.w;
            }
        }
        float y1v[2], y2v[2];
#pragma unroll
        for (int mm = 0; mm < 2; ++mm) {
            float s1 = E1, s2 = FA;
#pragma unroll
            for (int k = 0; k < 8; ++k) {
                s1 += u1[2 * mm + k] * we[k];
                s2 += u2[2 * mm + k] * wfa[k];
            }
            y1v[mm] = s1 > 0.f ? s1 : 0.f;
            y2v[mm] = s2 > 0.f ? s2 : 0.f;
        }
        int m0 = 2 * lane;
        if (m0 + 1 < L_S2) {
            *(float2*)&y1s[m0] = make_float2(y1v[0], y1v[1]);
            *(float2*)&y2s[m0] = make_float2(y2v[0], y2v[1]);
        } else if (m0 < L_S2) {         // m0 == 124
            y1s[m0] = y1v[0];
            y2s[m0] = y2v[0];
        }
        __builtin_amdgcn_wave_barrier();

        // ---- maxpool(4,4) + BN2/3 partial stats --------------------------
        float s1 = 0.f, q1 = 0.f, s2 = 0.f, q2 = 0.f;
        if (lane < L_MP) {
            float4 a = *(const float4*)&y1s[4 * lane];
            float4 bq = *(const float4*)&y2s[4 * lane];
            float v1 = fmaxf(fmaxf(a.x, a.y), fmaxf(a.z, a.w));
            float v2 = fmaxf(fmaxf(bq.x, bq.y), fmaxf(bq.z, bq.w));
            int bc = b * 32 + c;
            p1[bc * L_MP + lane] = v1;
            p2[bc * L_MP + lane] = v2;
            s1 = v1; q1 = v1 * v1; s2 = v2; q2 = v2 * v2;
        }
#pragma unroll
        for (int off = 32; off >= 1; off >>= 1) {
            s1 += __shfl_down(s1, off);
            q1 += __shfl_down(q1, off);
            s2 += __shfl_down(s2, off);
            q2 += __shfl_down(q2, off);
        }
        if (lane == 0) {
            atomicAdd(&bn_d[c],      (double)s1);
            atomicAdd(&bn_d[32 + c], (double)q1);
            atomicAdd(&bn_d[64 + c], (double)s2);
            atomicAdd(&bn_d[96 + c], (double)q2);
        }
        __builtin_amdgcn_wave_barrier();
    }
}

// ---------------- K4: finalize BN2 / BN3 ----------------------------------
__global__ void bn23_finalize_kernel(
    const double* __restrict__ bn_d,
    const float* __restrict__ bn2_g, const float* __restrict__ bn2_b,
    const float* __restrict__ bn3_g, const float* __restrict__ bn3_b,
    float* __restrict__ ad23)
{
    int t = threadIdx.x;
    if (t < 64) {
        int br = t >> 5, c = t & 31;
        double sum = bn_d[br * 64 + c], sq = bn_d[br * 64 + 32 + c];
        const double N = 1024.0 * 31.0;
        double mean = sum / N;
        double var = sq / N - mean * mean;
        float g  = br ? bn3_g[c] : bn2_g[c];
        float be = br ? bn3_b[c] : bn2_b[c];
        float alpha = g * (float)(1.0 / sqrt(var + 1e-5));
        ad23[br * 64 + c]      = alpha;
        ad23[br * 64 + 32 + c] = be - (float)mean * alpha;
    }
}

// ---------------- K5: BN apply + last Eventually + concat -----------------
__global__ __launch_bounds__(256) void final_ev_kernel(
    const float* __restrict__ p1, const float* __restrict__ p2,
    const float* __restrict__ e2w_g, const float* __restrict__ e2b_g,
    const float* __restrict__ f2w_g, const float* __restrict__ f2b_g,
    const float* __restrict__ ad23, float* __restrict__ z0)
{
    __shared__ float pr[2][32][31];
    __shared__ float w2s[2][32][8];
    __shared__ float al[2][32], de[2][32], eb[2][32];
    int b = blockIdx.x, tid = threadIdx.x;
    for (int i = tid; i < 992; i += 256) {
        pr[0][0][i] = p1[b * 992 + i];
        pr[1][0][i] = p2[b * 992 + i];
    }
    if (tid < 256) {
        w2s[0][0][tid] = e2w_g[tid];
        w2s[1][0][tid] = f2w_g[tid];
    }
    if (tid < 32) {
        al[0][tid] = ad23[tid];      de[0][tid] = ad23[32 + tid];
        al[1][tid] = ad23[64 + tid]; de[1][tid] = ad23[96 + tid];
        eb[0][tid] = e2b_g[tid];     eb[1][tid] = f2b_g[tid];
    }
    __syncthreads();
    for (int u = tid; u < 768; u += 256) {
        int br = u / 384, rem = u - br * 384;
        int c = rem / 12, tt = rem - c * 12;
        float a = al[br][c], d = de[br][c];
        float s = 1.f - eb[br][c];
#pragma unroll
        for (int k = 0; k < 8; ++k)
            s += (pr[br][c][2 * tt + k] * a + d) * w2s[br][c][k];
        z0[b * 768 + u] = s > 0.f ? s : 0.f;
    }
}

// ---------------- K6-8: fp32 GEMM 32x32 tile, 64 thr, 4x4 micro -----------
__global__ __launch_bounds__(64) void gemm_relu_kernel(
    const float* __restrict__ A, const float* __restrict__ B,
    const float* __restrict__ bias, float* __restrict__ C,
    int M, int N, int K)
{
    __shared__ __align__(16) float As[16][36];   // transposed: As[k][m]
    __shared__ __align__(16) float Bs[16][36];   // natural:    Bs[k][n]
    int tid = threadIdx.x;
    int tx = tid & 7, ty = tid >> 3;
    int m0 = blockIdx.y * 32, n0 = blockIdx.x * 32;
    float acc[4][4] = {};
    for (int k0 = 0; k0 < K; k0 += 16) {
#pragma unroll
        for (int v = 0; v < 2; ++v) {
            int q = tid + v * 64;
            int ar = q >> 2, ak = (q & 3) << 2;
            float4 a = *(const float4*)&A[(size_t)(m0 + ar) * K + k0 + ak];
            As[ak + 0][ar] = a.x; As[ak + 1][ar] = a.y;
            As[ak + 2][ar] = a.z; As[ak + 3][ar] = a.w;
            int br = q >> 3, bc = (q & 7) << 2;
            float4 bb = *(const float4*)&B[(size_t)(k0 + br) * N + n0 + bc];
            *(float4*)&Bs[br][bc] = bb;
        }
        __syncthreads();
#pragma unroll
        for (int kk = 0; kk < 16; ++kk) {
            float a[4], bb[4];
#pragma unroll
            for (int i = 0; i < 4; ++i) a[i] = As[kk][ty * 4 + i];
#pragma unroll
            for (int j = 0; j < 4; ++j) bb[j] = Bs[kk][tx * 4 + j];
#pragma unroll
            for (int i = 0; i < 4; ++i)
#pragma unroll
                for (int j = 0; j < 4; ++j)
                    acc[i][j] += a[i] * bb[j];
        }
        __syncthreads();
    }
#pragma unroll
    for (int i = 0; i < 4; ++i) {
        int m = m0 + ty * 4 + i;
#pragma unroll
        for (int j = 0; j < 4; ++j) {
            int n = n0 + tx * 4 + j;
            float v = acc[i][j] + bias[n];
            C[(size_t)m * N + n] = v > 0.f ? v : 0.f;
        }
    }
}

// ---------------- K9: last FC (N=10) --------------------------------------
__global__ __launch_bounds__(256) void fc4_kernel(
    const float* __restrict__ z3, const float* __restrict__ w4,
    const float* __restrict__ b4, float* __restrict__ out)
{
    int g = blockIdx.x * 256 + threadIdx.x;
    if (g >= 1024 * 10) return;
    int m = g / 10, n = g - m * 10;
    float acc = b4[n];
#pragma unroll 8
    for (int k = 0; k < 128; ++k)
        acc += z3[m * 128 + k] * w4[k * 10 + n];
    out[g] = acc > 0.f ? acc : 0.f;
}

// ---------------------------------------------------------------------------
extern "C" void kernel_launch(void* const* d_in, const int* in_sizes, int n_in,
                              void* d_out, int out_size, void* d_ws, size_t ws_size,
                              hipStream_t stream)
{
    (void)in_sizes; (void)n_in; (void)out_size; (void)ws_size;
    const float* x      = (const float*)d_in[0];
    const float* la_a   = (const float*)d_in[1];
    const float* la_b   = (const float*)d_in[2];
    const float* bn1_g  = (const float*)d_in[4];
    const float* bn1_b  = (const float*)d_in[5];
    const float* a1_w   = (const float*)d_in[6];
    const float* a1_b   = (const float*)d_in[7];
    const float* e1_w   = (const float*)d_in[8];
    const float* e1_b   = (const float*)d_in[9];
    const float* bn2_g  = (const float*)d_in[10];
    const float* bn2_b  = (const float*)d_in[11];
    const float* e2_w   = (const float*)d_in[12];
    const float* e2_b   = (const float*)d_in[13];
    const float* f1_w   = (const float*)d_in[14];
    const float* f1_b   = (const float*)d_in[15];
    const float* fa_w   = (const float*)d_in[16];
    const float* fa_b   = (const float*)d_in[17];
    const float* bn3_g  = (const float*)d_in[18];
    const float* bn3_b  = (const float*)d_in[19];
    const float* f2_w   = (const float*)d_in[20];
    const float* f2_b   = (const float*)d_in[21];
    const float* w1     = (const float*)d_in[22];
    const float* b1     = (const float*)d_in[23];
    const float* w2     = (const float*)d_in[24];
    const float* b2     = (const float*)d_in[25];
    const float* w3     = (const float*)d_in[26];
    const float* b3     = (const float*)d_in[27];
    const float* w4     = (const float*)d_in[28];
    const float* b4     = (const float*)d_in[29];
    float* out = (float*)d_out;

    char* w = (char*)d_ws;
    double* stats_d = (double*)(w + 0);
    double* bn_d    = (double*)(w + 256);
    float* g18      = (float*)(w + 1536);
    float* a1d1     = (float*)(w + 3840);
    float* ad23     = (float*)(w + 4096);
    float* p1       = (float*)(w + 8192);
    float* p2       = (float*)(w + 8192 + 4063232);
    float* z0       = (float*)(w + 8134656);
    float* z1       = (float*)(w + 11280384);
    float* z2       = (float*)(w + 15474688);
    float* z3       = (float*)(w + 17571840);

    zero_stats_kernel<<<1, 256, 0, stream>>>(stats_d);
    xstats_kernel<<<1024, 256, 0, stream>>>(x, stats_d);
    prep_kernel<<<1, 512, 0, stream>>>(stats_d, la_a, la_b, bn1_g, bn1_b, g18, a1d1);
    branches_kernel<<<1024, 512, 0, stream>>>(
        x, g18, a1d1, a1_w, a1_b, e1_w, e1_b, f1_w, f1_b, fa_w, fa_b,
        p1, p2, bn_d);
    bn23_finalize_kernel<<<1, 64, 0, stream>>>(bn_d, bn2_g, bn2_b, bn3_g, bn3_b, ad23);
    final_ev_kernel<<<1024, 256, 0, stream>>>(p1, p2, e2_w, e2_b, f2_w, f2_b, ad23, z0);
    gemm_relu_kernel<<<dim3(32, 32), 64, 0, stream>>>(z0, w1, b1, z1, 1024, 1024, 768);
    gemm_relu_kernel<<<dim3(16, 32), 64, 0, stream>>>(z1, w2, b2, z2, 1024, 512, 1024);
    gemm_relu_kernel<<<dim3(4, 32), 64, 0, stream>>>(z2, w3, b3, z3, 1024, 128, 512);
    fc4_kernel<<<40, 256, 0, stream>>>(z3, w4, b4, out);
}